// Round 9
// baseline (291.002 us; speedup 1.0000x reference)
//
#include <hip/hip_runtime.h>
#include <math.h>
#include <stdint.h>

#define Bn 8
#define Nn 2048
#define Cn 128
#define CP2 160         // 128 h-cols + w-col(=128) + 31 zero cols (den tile 32-wide)
#define NKB (Nn / 32)   // 64 k-blocks of 32

typedef _Float16 f16x8 __attribute__((ext_vector_type(8)));
typedef _Float16 f16x4 __attribute__((ext_vector_type(4)));
typedef _Float16 f16x2 __attribute__((ext_vector_type(2)));
typedef __fp16   fp16x2 __attribute__((ext_vector_type(2)));
typedef float    f32x16 __attribute__((ext_vector_type(16)));

// ---------------------------------------------------------------------------
// prep_kernel: v[c] = sum_d Ww[d][c]*aw[C+d];  vout[128] = b2 = Wb·aw2.
// ---------------------------------------------------------------------------
__global__ __launch_bounds__(256) void prep_kernel(const float* __restrict__ Ww,
                                                   const float* __restrict__ Wb,
                                                   const float* __restrict__ aw,
                                                   float* __restrict__ vout) {
    int tid = threadIdx.x;
    if (tid < 128) {
        float acc = 0.f;
#pragma unroll 16
        for (int d = 0; d < Cn; ++d) acc += Ww[d * Cn + tid] * aw[Cn + d];
        vout[tid] = acc;
    } else if (tid < 192) {
        int i = tid - 128;
        float p = Wb[i] * aw[Cn + i] + Wb[i + 64] * aw[Cn + i + 64];
        p += __shfl_xor(p, 32, 64);
        p += __shfl_xor(p, 16, 64);
        p += __shfl_xor(p, 8, 64);
        p += __shfl_xor(p, 4, 64);
        p += __shfl_xor(p, 2, 64);
        p += __shfl_xor(p, 1, 64);
        if (i == 0) vout[128] = p;
    }
}

// ---------------------------------------------------------------------------
// rows_kernel: per 16-row chunk: w = exp(h·v + b2);
//   hWt[b][kb][cp][ks] = f16(w_j*h[j][cp]) (cp<128), f16(w_j) at cp=128,
//   zeros cp 129..159 (32-wide denominator tile for 32x32 MFMA).
// grid = 8 x 128 = 1024 blocks, 256 threads.
// ---------------------------------------------------------------------------
__global__ __launch_bounds__(256) void rows_kernel(const float* __restrict__ h,
                                                   const float* __restrict__ vout,
                                                   _Float16* __restrict__ hWt) {
    __shared__ float tile[16][132];
    __shared__ float vsh[129];
    __shared__ float wsh[16];

    int bid = blockIdx.x;
    int b   = bid & 7;                   // XCD-aligned batch
    int n0  = (bid >> 3) << 4;
    int tid = threadIdx.x;

    if (tid < 129) vsh[tid] = vout[tid];
    {   // stage 16x128 h tile: 512 float4, 2 per thread
#pragma unroll
        for (int i = 0; i < 2; ++i) {
            int idx = tid + 256 * i;
            int r = idx >> 5, f4 = idx & 31;
            *(float4*)&tile[r][f4 * 4] =
                ((const float4*)(h + (size_t)(b * Nn + n0 + r) * Cn))[f4];
        }
    }
    __syncthreads();

    {   // w = exp(h·v + b2): 16 threads per row
        int r = tid >> 4, g = tid & 15;
        float acc = 0.f;
#pragma unroll
        for (int ii = 0; ii < 8; ++ii) {
            int i = g * 8 + ii;
            acc += tile[r][i] * vsh[i];
        }
        acc += __shfl_xor(acc, 1, 64);
        acc += __shfl_xor(acc, 2, 64);
        acc += __shfl_xor(acc, 4, 64);
        acc += __shfl_xor(acc, 8, 64);
        if (g == 0) wsh[r] = expf(acc + vsh[128]);
    }
    __syncthreads();

    {   // hWt stores: 160 cp x 8 pairs = 1280 f16x2 = 5 x 256 exact
        int kb = n0 >> 5, khalf = (n0 >> 4) & 1;
        _Float16* hWb = hWt + ((size_t)(b * NKB + kb) * CP2) * 32 + khalf * 16;
#pragma unroll
        for (int i = 0; i < 5; ++i) {
            int idx = tid + 256 * i;     // 0..1279
            int cp = idx >> 3, p = idx & 7;
            int r0 = p * 2;
            f16x2 v2;
            if (cp < 128) {
                v2[0] = (_Float16)(wsh[r0] * tile[r0][cp]);
                v2[1] = (_Float16)(wsh[r0 + 1] * tile[r0 + 1][cp]);
            } else if (cp == 128) {
                v2[0] = (_Float16)wsh[r0];
                v2[1] = (_Float16)wsh[r0 + 1];
            } else {
                v2[0] = (_Float16)0.f;
                v2[1] = (_Float16)0.f;
            }
            *(f16x2*)(hWb + (size_t)cp * 32 + p * 2) = v2;
        }
    }
}

// ---------------------------------------------------------------------------
// attn_kernel: f16 GEMM out' = A @ hW via mfma_f32_32x32x16_f16 with ZERO
// barriers in the K-loop.  A-frags (32 rows x 8 k's) load straight from
// global as 2 float4/lane + cvt; B-frags are 16-B contiguous from L2-hot
// hWt.  Block = 512 thr = 8 waves = 2 m-tiles(32) x 4 c-tiles(32); c0-waves
// also accumulate the denominator tile (cp 128..159, col 0 = sum A*w) off
// the same A-frag.  grid = 8 x 32 = 256 blocks (1/CU).  Epilogue: den to
// LDS, one barrier, normalize, coalesced stores.
// ---------------------------------------------------------------------------
__global__ __launch_bounds__(512, 2) void attn_kernel(const float* __restrict__ A,
                                                      const _Float16* __restrict__ hWt,
                                                      float* __restrict__ out) {
    __shared__ float den_lds[64];

    int bid = blockIdx.x;
    int b   = bid & 7;                   // XCD-aligned batch
    int i0  = (bid >> 3) << 6;           // 32 row-blocks of 64
    int tid = threadIdx.x;
    int wv  = tid >> 6, l = tid & 63;
    int mi  = wv & 1, ci = wv >> 1;      // m-tile 0/1, c-tile 0..3
    int n   = l & 31, kb2 = l >> 5;      // A: row-in-tile / B: col-in-tile; k-subblock

    // lane's A row pointer, pre-offset by its k-phase (kb2*8)
    const float* Arow = A + (size_t)(b * Nn + i0 + mi * 32 + n) * Nn + kb2 * 8;
    const _Float16* hWb = hWt + (size_t)b * NKB * CP2 * 32;
    int cp  = ci * 32 + n;               // this lane's B column
    int cpd = 128 + n;                   // denominator-tile column

    f32x16 acc  = (f32x16)(0.f);
    f32x16 dacc = (f32x16)(0.f);
    bool do_den = (ci == 0);

#pragma unroll 4
    for (int kk = 0; kk < 128; ++kk) {   // K=16 per step
        // A-frag: 8 consecutive f32 -> f16 (k = kb2*8 + jj)
        float4 x = *(const float4*)(Arow + kk * 16);
        float4 y = *(const float4*)(Arow + kk * 16 + 4);
        union { fp16x2 h2[4]; f16x8 v; } u;
        u.h2[0] = __builtin_amdgcn_cvt_pkrtz(x.x, x.y);
        u.h2[1] = __builtin_amdgcn_cvt_pkrtz(x.z, x.w);
        u.h2[2] = __builtin_amdgcn_cvt_pkrtz(y.x, y.y);
        u.h2[3] = __builtin_amdgcn_cvt_pkrtz(y.z, y.w);

        // B-frag: j0 = kk*16 + kb2*8 -> (kb, ks); 16 B contiguous
        int j0 = kk * 16 + kb2 * 8;
        const _Float16* bp = hWb + ((size_t)(j0 >> 5) * CP2) * 32 + (j0 & 31);
        f16x8 bf = *(const f16x8*)(bp + (size_t)cp * 32);
        acc = __builtin_amdgcn_mfma_f32_32x32x16_f16(u.v, bf, acc, 0, 0, 0);
        if (do_den) {
            f16x8 bd = *(const f16x8*)(bp + (size_t)cpd * 32);
            dacc = __builtin_amdgcn_mfma_f32_32x32x16_f16(u.v, bd, dacc, 0, 0, 0);
        }
    }

    // den = den-tile col 0 (cp 128): lanes with n==0 hold it
    if (do_den && n == 0) {
#pragma unroll
        for (int r = 0; r < 16; ++r) {
            int row = (r & 3) + 8 * (r >> 2) + 4 * kb2;
            den_lds[mi * 32 + row] = dacc[r];
        }
    }
    __syncthreads();

    // normalize + store: D layout col = l&31, row = (r&3)+8*(r>>2)+4*(l>>5)
#pragma unroll
    for (int r = 0; r < 16; ++r) {
        int row = (r & 3) + 8 * (r >> 2) + 4 * kb2;
        float inv = 1.f / den_lds[mi * 32 + row];
        out[(size_t)(b * Nn + i0 + mi * 32 + row) * Cn + ci * 32 + n] = acc[r] * inv;
    }
}

// ---------------------------------------------------------------------------
extern "C" void kernel_launch(void* const* d_in, const int* in_sizes, int n_in,
                              void* d_out, int out_size, void* d_ws, size_t ws_size,
                              hipStream_t stream) {
    const float* h  = (const float*)d_in[0];
    const float* A  = (const float*)d_in[1];
    const float* Ww = (const float*)d_in[2];
    const float* Wb = (const float*)d_in[3];
    const float* aw = (const float*)d_in[4];
    // d_in[5] = a_b : cancels in the row normalization, unused
    float* out = (float*)d_out;

    char* ws = (char*)d_ws;
    _Float16* hWt  = (_Float16*)ws;                                   // 5.24 MB
    float*    vout = (float*)(ws + (size_t)Bn * NKB * CP2 * 32 * 2);  // 129 f32

    prep_kernel<<<1, 256, 0, stream>>>(Ww, Wb, aw, vout);
    rows_kernel<<<Bn * (Nn / 16), 256, 0, stream>>>(h, vout, hWt);
    attn_kernel<<<Bn * (Nn / 64), 512, 0, stream>>>(A, hWt, out);
}